// Round 3
// baseline (328.238 us; speedup 1.0000x reference)
//
#include <hip/hip_runtime.h>
#include <hip/hip_bf16.h>
#include <math.h>

#define BB 8
#define TT 64
#define DD 1024
#define SS 32
#define EE 16
#define VV 50257
#define BT (BB*TT)   // 512
#define BS (BB*SS)   // 256

// pointer_probs zero-fill distribution: 512*50257 floats = 6,432,896 float4s
#define N4TOT 6432896
#define Z0END 2144300   // K0 zeroes [0, Z0END)
#define Z1END 4288600   // K1 zeroes [Z0END, Z1END)
#define ZB0 512
#define ZB1 1024
#define ZB2 512

typedef __attribute__((ext_vector_type(8))) short short8;   // 8 bf16 (4 VGPRs)
typedef __attribute__((ext_vector_type(4))) float floatx4;  // 4 fp32

static __device__ inline unsigned short f2bf(float x) {
    __hip_bfloat16 h = __float2bfloat16(x);   // RNE
    union { __hip_bfloat16 h; unsigned short u; } cv; cv.h = h;
    return cv.u;
}

static __device__ inline void gl_lds16(const void* g, void* l) {
    __builtin_amdgcn_global_load_lds(
        (const __attribute__((address_space(1))) void*)g,
        (__attribute__((address_space(3))) void*)l, 16, 0, 0);
}

static __device__ inline void zero_range(float4* pv, int start, int end,
                                         int zb, int nzb, int nthr) {
    const float4 z4 = make_float4(0.f, 0.f, 0.f, 0.f);
    for (int i = start + zb * nthr + (int)threadIdx.x; i < end; i += nzb * nthr)
        pv[i] = z4;
}

// ---------------------------------------------------------------------------
// K0 prep:
//  blocks [0,768):     convert dec|scene row -> Xb[row][k] bf16
//  blocks [768,1280):  transpose-convert Wq|Wk -> Wt[sel][n][k] bf16
//  blocks [1280,2048): dots dw[bt]=dec.Wp0, mw[bs]=scene.Wp1 (f32 exact)
//  blocks [2048,2048+ZB0): zero pp slice 0 (overlaps with compute)
// ---------------------------------------------------------------------------
__global__ __launch_bounds__(256) void prep_kernel(
    const float* __restrict__ dec, const float* __restrict__ scene,
    const float* __restrict__ Wq, const float* __restrict__ Wk,
    const float* __restrict__ Wp,
    unsigned short* __restrict__ Xb, unsigned short* __restrict__ Wt,
    float* __restrict__ dw, float* __restrict__ mw,
    float* __restrict__ pp)
{
    __shared__ float tile[64][65];
    const int bid = blockIdx.x;
    const int t = threadIdx.x;
    if (bid < 768) {                       // ---- convert X rows
        const int row = bid;
        const float* src = (row < BT) ? dec + (size_t)row * DD
                                      : scene + (size_t)(row - BT) * DD;
        const float4 v = *(const float4*)&src[t * 4];
        ushort4 u;
        u.x = f2bf(v.x); u.y = f2bf(v.y); u.z = f2bf(v.z); u.w = f2bf(v.w);
        *(ushort4*)&Xb[(size_t)row * DD + t * 4] = u;
    } else if (bid < 1280) {               // ---- transpose-convert W
        const int tb = bid - 768;
        const int sel = tb >> 8;           // 0=Wq, 1=Wk
        const int tt8 = tb & 255;
        const int k0 = (tt8 >> 4) * 64, n0 = (tt8 & 15) * 64;
        const float* Wsrc = sel ? Wk : Wq;
        const int c4 = (t & 15) * 4;
        #pragma unroll
        for (int i = 0; i < 4; ++i) {
            const int r = (t >> 4) + 16 * i;
            const float4 v = *(const float4*)&Wsrc[(size_t)(k0 + r) * DD + n0 + c4];
            tile[r][c4 + 0] = v.x; tile[r][c4 + 1] = v.y;
            tile[r][c4 + 2] = v.z; tile[r][c4 + 3] = v.w;
        }
        __syncthreads();
        #pragma unroll
        for (int i = 0; i < 4; ++i) {
            const int n = (t >> 4) + 16 * i;
            ushort4 u;
            u.x = f2bf(tile[c4 + 0][n]); u.y = f2bf(tile[c4 + 1][n]);
            u.z = f2bf(tile[c4 + 2][n]); u.w = f2bf(tile[c4 + 3][n]);
            *(ushort4*)&Wt[(size_t)sel * DD * DD + (size_t)(n0 + n) * DD + k0 + c4] = u;
        }
    } else if (bid < 2048) {               // ---- Wp dots (f32 exact)
        const int di = bid - 1280;         // 0..767
        const float* x; const float* wp; float* outp;
        if (di < BT) { x = dec   + (size_t)di * DD;        wp = Wp;      outp = dw + di; }
        else         { x = scene + (size_t)(di - BT) * DD; wp = Wp + DD; outp = mw + (di - BT); }
        float s = 0.f;
        #pragma unroll
        for (int i = 0; i < 4; ++i) s += x[t + 256 * i] * wp[t + 256 * i];
        for (int off = 32; off; off >>= 1) s += __shfl_down(s, off);
        if ((t & 63) == 0) tile[0][t >> 6] = s;
        __syncthreads();
        if (t == 0) *outp = tile[0][0] + tile[0][1] + tile[0][2] + tile[0][3];
    } else {                               // ---- zero pp slice 0
        zero_range((float4*)pp, 0, Z0END, bid - 2048, ZB0, 256);
    }
}

// ---------------------------------------------------------------------------
// K1 MFMA GEMM: Y[768][1024] = Xb @ W(sel by row group), f32 out + bias.
// Blocks [0,384): 128 thr (2 waves), tile 32(M)x64(N), K-step 32.
// Blocks [384,384+ZB1): zero pp slice 1.
// ---------------------------------------------------------------------------
__global__ __launch_bounds__(128) void gemm_mfma(
    const unsigned short* __restrict__ Xb, const unsigned short* __restrict__ Wt,
    const float* __restrict__ bq, const float* __restrict__ bk,
    float* __restrict__ qo, float* __restrict__ ko,
    float* __restrict__ pp)
{
    __shared__ unsigned short As[32 * 32];   // [m][k] 2 KB
    __shared__ unsigned short Bs[64 * 32];   // [n][k] 4 KB
    const int bid = blockIdx.x;
    if (bid >= 384) {                        // ---- zero pp slice 1
        zero_range((float4*)pp, Z0END, Z1END, bid - 384, ZB1, 128);
        return;
    }
    const int bm = bid >> 4;                 // 0..23
    const int bn = bid & 15;                 // 0..15
    const int m0 = bm * 32, n0 = bn * 64;
    const bool isq = (bm < 16);
    const unsigned short* Wsel = Wt + (isq ? 0 : (size_t)DD * DD);
    const int tid = threadIdx.x;
    const int w = tid >> 6, l = tid & 63;

    const int arow = 16 * w + (l >> 2);      // staging row (A)
    const int kb8  = (l & 3) * 8;            // staging k offset (elems)
    floatx4 acc[4] = {{0.f,0.f,0.f,0.f},{0.f,0.f,0.f,0.f},
                      {0.f,0.f,0.f,0.f},{0.f,0.f,0.f,0.f}};

    for (int k0 = 0; k0 < DD; k0 += 32) {
        __syncthreads();
        gl_lds16(&Xb[(size_t)(m0 + arow) * DD + k0 + kb8], &As[w * 512]);
        #pragma unroll
        for (int i = 0; i < 2; ++i) {
            const int brow = 32 * w + 16 * i + (l >> 2);
            gl_lds16(&Wsel[(size_t)(n0 + brow) * DD + k0 + kb8],
                     &Bs[w * 1024 + i * 512]);
        }
        __syncthreads();
        const short8 a = *(const short8*)&As[(16 * w + (l & 15)) * 32 + (l >> 4) * 8];
        #pragma unroll
        for (int j = 0; j < 4; ++j) {
            const short8 b = *(const short8*)&Bs[(16 * j + (l & 15)) * 32 + (l >> 4) * 8];
            acc[j] = __builtin_amdgcn_mfma_f32_16x16x32_bf16(a, b, acc[j], 0, 0, 0);
        }
    }
    // C/D: col = lane&15, row = (lane>>4)*4 + reg   [m89-verified]
    #pragma unroll
    for (int j = 0; j < 4; ++j) {
        const int gcol = n0 + 16 * j + (l & 15);
        const float bias = isq ? bq[gcol] : bk[gcol];
        #pragma unroll
        for (int r = 0; r < 4; ++r) {
            const int grow = m0 + 16 * w + (l >> 4) * 4 + r;
            const float val = acc[j][r] + bias;
            if (isq) qo[(size_t)grow * DD + gcol] = val;
            else     ko[(size_t)(grow - BT) * DD + gcol] = val;
        }
    }
}

// ---------------------------------------------------------------------------
// K2: blocks [0,512) attention+p_gen per (b,t); [512,768) salience per (b,s);
//     [768,768+ZB2) zero pp slice 2.
// ---------------------------------------------------------------------------
__global__ __launch_bounds__(256) void attn_sal_kernel(
    const float* __restrict__ qm, const float* __restrict__ km,
    const float* __restrict__ dec, const float* __restrict__ emb,
    const int* __restrict__ ids,
    const float* __restrict__ dwv, const float* __restrict__ mwv,
    const float* __restrict__ bp,
    float* __restrict__ attn_out, float* __restrict__ pgen_out,
    float* __restrict__ sal_out, float* __restrict__ pp)
{
    __shared__ __align__(16) float qs[DD];
    __shared__ float sc[SS];
    __shared__ int lid[EE];
    const int tid = threadIdx.x;
    const int w = tid >> 6, lane = tid & 63;

    if (blockIdx.x < BT) {
        // ---------------- attention + p_gen ----------------
        const int bt = blockIdx.x;
        const int b  = bt / TT;
        *(float4*)&qs[tid * 4] = *(const float4*)&qm[(size_t)bt * DD + tid * 4];
        __syncthreads();
        for (int j = 0; j < 8; ++j) {
            const int s = w * 8 + j;
            const float* kr = km + (size_t)(b * SS + s) * DD;
            float accv = 0.f;
            #pragma unroll
            for (int i = 0; i < 4; ++i) {
                const float4 qv = *(const float4*)&qs[4 * lane + 256 * i];
                const float4 kv = *(const float4*)&kr[4 * lane + 256 * i];
                accv += qv.x * kv.x + qv.y * kv.y + qv.z * kv.z + qv.w * kv.w;
            }
            for (int off = 32; off; off >>= 1) accv += __shfl_down(accv, off);
            if (lane == 0) sc[s] = accv * 0.03125f;
        }
        __syncthreads();
        if (tid < 64) {
            float v = (lane < SS) ? sc[lane] : -INFINITY;
            float m = v;
            for (int off = 32; off; off >>= 1) m = fmaxf(m, __shfl_xor(m, off));
            float e = (lane < SS) ? __expf(v - m) : 0.f;
            float sum = e;
            for (int off = 32; off; off >>= 1) sum += __shfl_xor(sum, off);
            const float a = e / sum;
            float g = (lane < SS) ? a * mwv[b * SS + lane] : 0.f;
            for (int off = 32; off; off >>= 1) g += __shfl_xor(g, off);
            if (lane < SS) attn_out[bt * SS + lane] = a;
            if (lane == 0) {
                const float z = dwv[bt] + g + bp[0] - 0.5f;
                pgen_out[bt] = 1.0f / (1.0f + __expf(-10.0f * z));
            }
        }
    } else if (blockIdx.x < BT + BS) {
        // ---------------- salience ----------------
        const int bs = blockIdx.x - BT;     // 0..255
        const int b  = bs / SS;
        const float* dl = dec + (size_t)(b * TT + (TT - 1)) * DD;
        *(float4*)&qs[tid * 4] = *(const float4*)&dl[tid * 4];
        if (tid < EE) lid[tid] = ids[bs * EE + tid];
        __syncthreads();
        for (int j = 0; j < 4; ++j) {
            const int e = w * 4 + j;
            const float* er = emb + (size_t)lid[e] * DD;
            float accv = 0.f;
            #pragma unroll
            for (int i = 0; i < 4; ++i) {
                const float4 dv = *(const float4*)&qs[4 * lane + 256 * i];
                const float4 ev = *(const float4*)&er[4 * lane + 256 * i];
                accv += dv.x * ev.x + dv.y * ev.y + dv.z * ev.z + dv.w * ev.w;
            }
            for (int off = 32; off; off >>= 1) accv += __shfl_down(accv, off);
            if (lane == 0) sc[e] = accv;
        }
        __syncthreads();
        if (tid == 0) {
            float m = -INFINITY;
            for (int e = 0; e < EE; ++e) m = fmaxf(m, sc[e]);
            float ex[EE]; float sum = 0.f;
            for (int e = 0; e < EE; ++e) { ex[e] = __expf(sc[e] - m); sum += ex[e]; }
            const float inv = 1.0f / sum;
            for (int e = 0; e < EE; ++e) {
                bool dup = false;
                for (int e2 = e + 1; e2 < EE; ++e2)
                    if (lid[e2] == lid[e]) { dup = true; break; }
                sal_out[bs * EE + e] = dup ? 0.f : ex[e] * inv;
            }
        }
    } else {                               // ---- zero pp slice 2
        zero_range((float4*)pp, Z1END, N4TOT, blockIdx.x - (BT + BS), ZB2, 256);
    }
}

// ---------------------------------------------------------------------------
// K3 scatter-only: one block per (b,t) row; pp rows already zeroed upstream.
// ---------------------------------------------------------------------------
__global__ __launch_bounds__(256) void scatter_kernel(
    const float* __restrict__ attn, const float* __restrict__ sal,
    const int* __restrict__ ids, float* __restrict__ pp)
{
    __shared__ float at[SS];
    const int bt = blockIdx.x;
    const int b  = bt / TT;
    const int tid = threadIdx.x;
    if (tid < SS) at[tid] = attn[bt * SS + tid];
    __syncthreads();
    float* row = pp + (size_t)bt * VV;
    for (int i = tid; i < SS * EE; i += 256) {
        const int s = i >> 4, e = i & 15;
        const float v = at[s] * sal[(b * SS + s) * EE + e];
        atomicAdd(&row[ids[(b * SS + s) * EE + e]], v);
    }
}

extern "C" void kernel_launch(void* const* d_in, const int* in_sizes, int n_in,
                              void* d_out, int out_size, void* d_ws, size_t ws_size,
                              hipStream_t stream) {
    (void)in_sizes; (void)n_in; (void)ws_size; (void)out_size;
    const float* dec   = (const float*)d_in[0];
    const float* scene = (const float*)d_in[1];
    const float* emb   = (const float*)d_in[2];
    const int*   ids   = (const int*)  d_in[3];
    const float* Wq    = (const float*)d_in[4];
    const float* bq    = (const float*)d_in[5];
    const float* Wk    = (const float*)d_in[6];
    const float* bk    = (const float*)d_in[7];
    const float* Wp    = (const float*)d_in[8];
    const float* bp    = (const float*)d_in[9];
    float* out = (float*)d_out;          // [0..511] p_gen, then pointer_probs
    float* ws  = (float*)d_ws;
    float* pp  = out + 512;

    float* q    = ws;                           // 512*1024
    float* kbuf = q    + 512 * 1024;            // 256*1024
    float* attn = kbuf + 256 * 1024;            // 512*32
    float* sal  = attn + 512 * 32;              // 256*16
    float* dw   = sal  + 256 * 16;              // 512
    float* mw   = dw   + 512;                   // 256
    unsigned short* Xb = (unsigned short*)(mw + 256);     // 768*1024 bf16
    unsigned short* Wt = Xb + 768 * 1024;                 // 2*1024*1024 bf16

    prep_kernel<<<2048 + ZB0, 256, 0, stream>>>(dec, scene, Wq, Wk, Wp,
                                                Xb, Wt, dw, mw, pp);
    gemm_mfma<<<384 + ZB1, 128, 0, stream>>>(Xb, Wt, bq, bk, q, kbuf, pp);
    attn_sal_kernel<<<768 + ZB2, 256, 0, stream>>>(q, kbuf, dec, emb, ids,
                                                   dw, mw, bp, attn, out, sal, pp);
    scatter_kernel<<<512, 256, 0, stream>>>(attn, sal, ids, pp);
}